// Round 2
// baseline (145.294 us; speedup 1.0000x reference)
//
#include <hip/hip_runtime.h>
#include <hip/hip_bf16.h>
#include <stdint.h>

#define BB 32
#define NN 128
#define DD 64
#define HH 128

__device__ __forceinline__ float bflo(uint32_t u){ union{uint32_t u;float f;} c; c.u = u<<16; return c.f; }
__device__ __forceinline__ float bfhi(uint32_t u){ union{uint32_t u;float f;} c; c.u = u & 0xffff0000u; return c.f; }
__device__ __forceinline__ uint32_t packbf(float lo, float hi){
  __hip_bfloat16 a = __float2bfloat16(lo);
  __hip_bfloat16 b = __float2bfloat16(hi);
  uint16_t ua = *(uint16_t*)&a, ub = *(uint16_t*)&b;
  return (uint32_t)ua | ((uint32_t)ub<<16);
}

// K0: M = W2 @ U1[64:], c0 = b2 @ U1[64:] + ub1   (update-net precomposition)
__global__ void k0_precompose(const float* __restrict__ W2,
                              const float* __restrict__ b2,
                              const float* __restrict__ U1,
                              const float* __restrict__ ub1,
                              float* __restrict__ M, float* __restrict__ c0){
  int c = threadIdx.x;          // 0..127
  int hb = blockIdx.x;          // 0..128 (128 = c0 block)
  if(hb < HH){
    float acc = 0.f;
    for(int k=0;k<HH;k++)
      acc += W2[hb*HH+k] * U1[(DD+k)*HH+c];
    M[hb*HH+c] = acc;
  } else {
    float acc = ub1[c];
    for(int k=0;k<HH;k++)
      acc += b2[k] * U1[(DD+k)*HH+c];
    c0[c] = acc;
  }
}

// K1: Pm = x@W1[:64]+b1, Qm = x@W1[64:], Pa = x@A1[:64]+ab1, Qa = x@A1[64:]
// Qm packed bf16 (h, h+64) per dword: Qmp[b][j][l]    l = h&63
// Qa packed bf16 (j, j+64) per dword, transposed: QaTp[b][h][l]  l = j&63
__global__ void k1_proj(const float* __restrict__ x,
                        const float* __restrict__ W1,
                        const float* __restrict__ b1,
                        const float* __restrict__ A1,
                        const float* __restrict__ ab1,
                        float* __restrict__ Pm, float* __restrict__ Pa,
                        uint32_t* __restrict__ Qmp, uint32_t* __restrict__ QaTp){
  const int g = blockIdx.x;   // 0..15 -> jb = 4g
  const int b = blockIdx.y;   // 0..31
  const int t = threadIdx.x;  // 0..127 = h
  const int jb = g*4;
  __shared__ float xs[8][64];     // 8 rows: jb..jb+3, jb+64..jb+67
  __shared__ float qmS[8][128];
  for(int k=0;k<4;k++){
    int idx = t + k*128;
    int r = idx >> 6, d = idx & 63;
    int gr = (r<4) ? (jb+r) : (jb + r - 4 + 64);
    xs[r][d] = x[(b*NN+gr)*DD + d];
  }
  __syncthreads();
  float pm[8], qm[8], pa[8], qa[8];
  #pragma unroll
  for(int r=0;r<8;r++){ pm[r]=0.f;qm[r]=0.f;pa[r]=0.f;qa[r]=0.f; }
  for(int d=0; d<DD; d++){
    float w1a = W1[d*HH + t];
    float w1b = W1[(DD+d)*HH + t];
    float a1a = A1[d*HH + t];
    float a1b = A1[(DD+d)*HH + t];
    #pragma unroll
    for(int r=0;r<8;r++){
      float xv = xs[r][d];
      pm[r] += xv*w1a; qm[r] += xv*w1b;
      pa[r] += xv*a1a; qa[r] += xv*a1b;
    }
  }
  float b1v = b1[t], ab1v = ab1[t];
  #pragma unroll
  for(int r=0;r<8;r++){
    int gr = (r<4) ? (jb+r) : (jb + r - 4 + 64);
    Pm[(b*NN+gr)*HH + t] = pm[r] + b1v;
    Pa[(b*NN+gr)*HH + t] = pa[r] + ab1v;
    qmS[r][t] = qm[r];
  }
  // Qa transpose-pack: this thread owns h=t for rows (jb+p, jb+p+64)
  #pragma unroll
  for(int p=0;p<4;p++)
    QaTp[(b*HH + t)*64 + (jb+p)] = packbf(qa[p], qa[p+4]);
  __syncthreads();
  // Qm pack (h, h+64) pairs
  for(int k=0;k<4;k++){
    int idx = t + k*128;              // 0..511
    int r = idx >> 6, l = idx & 63;
    int gr = (r<4) ? (jb+r) : (jb + r - 4 + 64);
    Qmp[(b*NN+gr)*64 + l] = packbf(qmS[r][l], qmS[r][l+64]);
  }
}

// K2a: logits_ij = sum_h relu(Pa_i[h] + Qa_j[h]) * A2[h]; masked softmax over j
__global__ void k2a_attn(const float* __restrict__ Pa,
                         const uint32_t* __restrict__ QaTp,
                         const float* __restrict__ A2,
                         const int* __restrict__ masks,
                         float* __restrict__ attn){
  const int it = blockIdx.x;     // 0..15, 8 i's each
  const int b  = blockIdx.y;
  const int t = threadIdx.x;     // 0..255
  const int wave = t>>6, lane = t&63;
  __shared__ uint32_t qaS[HH*64];   // 32 KB, [h][l] lane=j
  __shared__ float paS[8*HH];       // 4 KB
  __shared__ float a2S[HH];
  for(int k=0;k<32;k++) qaS[t + k*256] = QaTp[(size_t)b*HH*64 + t + k*256];
  for(int k=0;k<4;k++){
    int idx = t + k*256; int r = idx>>7, h = idx&127;
    paS[idx] = Pa[(b*NN + it*8 + r)*HH + h];
  }
  if(t < HH) a2S[t] = A2[t];
  __syncthreads();
  const int i0 = wave*2, i1 = wave*2+1;   // local i within tile
  float a00=0.f,a01=0.f,a10=0.f,a11=0.f;  // (i, j=lane / j=lane+64)
  for(int h=0; h<HH; h++){
    uint32_t qd = qaS[h*64 + lane];
    float qlo = bflo(qd), qhi = bfhi(qd);
    float a2 = a2S[h];
    float p0 = paS[i0*HH + h], p1 = paS[i1*HH + h];
    a00 += fmaxf(p0+qlo,0.f)*a2;  a01 += fmaxf(p0+qhi,0.f)*a2;
    a10 += fmaxf(p1+qlo,0.f)*a2;  a11 += fmaxf(p1+qhi,0.f)*a2;
  }
  const int m0 = masks[b*NN + lane];
  const int m1 = masks[b*NN + 64 + lane];
  const float NEG = -3.0e38f;
  #pragma unroll
  for(int ii=0; ii<2; ii++){
    float x0 = ii ? a10 : a00, x1 = ii ? a11 : a01;
    int iglob = b*NN + it*8 + (ii ? i1 : i0);
    float l0 = m0 ? x0 : NEG, l1 = m1 ? x1 : NEG;
    float v = fmaxf(l0, l1);
    for(int off=32; off>=1; off>>=1) v = fmaxf(v, __shfl_xor(v, off));
    float e0 = m0 ? __expf(x0 - v) : 0.f;
    float e1 = m1 ? __expf(x1 - v) : 0.f;
    float s = e0 + e1;
    for(int off=32; off>=1; off>>=1) s += __shfl_xor(s, off);
    float inv = (s > 0.f) ? (1.f/s) : 0.f;
    attn[iglob*NN + lane]      = e0*inv;
    attn[iglob*NN + 64 + lane] = e1*inv;
  }
}

// K2b: hbar_i[h] = sum_j attn_ij * relu(Pm_i[h] + Qm_j[h])
__global__ void k2b_hbar(const float* __restrict__ Pm,
                         const uint32_t* __restrict__ Qmp,
                         const float* __restrict__ attn,
                         float* __restrict__ hbar){
  const int it = blockIdx.x; const int b = blockIdx.y;
  const int t = threadIdx.x; const int wave=t>>6, lane=t&63;
  __shared__ uint32_t qmS[NN*64];   // 32 KB, [j][l] lane=h
  __shared__ float atS[8*NN];       // 4 KB
  for(int k=0;k<32;k++) qmS[t + k*256] = Qmp[(size_t)b*NN*64 + t + k*256];
  for(int k=0;k<4;k++){
    int idx = t + k*256; int r = idx>>7, j = idx&127;
    atS[idx] = attn[(b*NN + it*8 + r)*NN + j];
  }
  __syncthreads();
  const int i0 = wave*2, i1 = i0+1;
  const int gi0 = b*NN + it*8 + i0, gi1 = gi0 + 1;
  float pm00 = Pm[gi0*HH + lane],     pm01 = Pm[gi0*HH + 64 + lane];
  float pm10 = Pm[gi1*HH + lane],     pm11 = Pm[gi1*HH + 64 + lane];
  float h00=0.f,h01=0.f,h10=0.f,h11=0.f;
  for(int j=0;j<NN;j++){
    uint32_t qd = qmS[j*64 + lane];
    float qlo = bflo(qd), qhi = bfhi(qd);
    float at0 = atS[i0*NN + j], at1 = atS[i1*NN + j];
    h00 += at0*fmaxf(pm00+qlo,0.f);
    h01 += at0*fmaxf(pm01+qhi,0.f);
    h10 += at1*fmaxf(pm10+qlo,0.f);
    h11 += at1*fmaxf(pm11+qhi,0.f);
  }
  hbar[gi0*HH + lane]      = h00;
  hbar[gi0*HH + 64 + lane] = h01;
  hbar[gi1*HH + lane]      = h10;
  hbar[gi1*HH + 64 + lane] = h11;
}

// K3: hidden = relu(x@U1[:64] + hbar@M + c0); out = x + hidden@U2 + ub2
__global__ void k3_update(const float* __restrict__ x,
                          const float* __restrict__ hbar,
                          const float* __restrict__ M,
                          const float* __restrict__ c0,
                          const float* __restrict__ U1,
                          const float* __restrict__ U2,
                          const float* __restrict__ ub2,
                          float* __restrict__ out){
  const int bid = blockIdx.x;   // 0..255, 16 rows each
  const int t = threadIdx.x;    // 0..255
  const int r0 = bid*16;
  __shared__ float xs[16][64];     // 4 KB
  __shared__ float hb[16][128];    // 8 KB
  __shared__ float hidS[16][128];  // 8 KB
  __shared__ float c0S[128];
  for(int k=0;k<4;k++){ int idx=t+k*256; int r=idx>>6, d=idx&63;
    xs[r][d] = x[(r0+r)*DD + d]; }
  for(int k=0;k<8;k++){ int idx=t+k*256; int r=idx>>7, h=idx&127;
    hb[r][h] = hbar[(r0+r)*HH + h]; }
  if(t<128) c0S[t] = c0[t];
  __syncthreads();
  {
    const int c = t & 127, g = t>>7;   // g: row-group of 8
    float acc[8];
    #pragma unroll
    for(int r=0;r<8;r++) acc[r]=0.f;
    for(int d=0; d<DD; d++){
      float u = U1[d*HH + c];
      #pragma unroll
      for(int r=0;r<8;r++) acc[r] += xs[g*8+r][d]*u;
    }
    for(int h=0; h<HH; h++){
      float mv = M[h*HH + c];
      #pragma unroll
      for(int r=0;r<8;r++) acc[r] += hb[g*8+r][h]*mv;
    }
    float cc = c0S[c];
    #pragma unroll
    for(int r=0;r<8;r++) hidS[g*8+r][c] = fmaxf(acc[r]+cc, 0.f);
  }
  __syncthreads();
  {
    const int dcol = t & 63, rg = t>>6;  // rg: row-group of 4
    float acc2[4];
    #pragma unroll
    for(int r=0;r<4;r++) acc2[r]=0.f;
    for(int c=0;c<HH;c++){
      float u2 = U2[c*DD + dcol];
      #pragma unroll
      for(int r=0;r<4;r++) acc2[r] += hidS[rg*4+r][c]*u2;
    }
    float ub = ub2[dcol];
    #pragma unroll
    for(int r=0;r<4;r++){
      int row = r0 + rg*4 + r;
      out[row*DD + dcol] = xs[rg*4+r][dcol] + acc2[r] + ub;
    }
  }
}

extern "C" void kernel_launch(void* const* d_in, const int* in_sizes, int n_in,
                              void* d_out, int out_size, void* d_ws, size_t ws_size,
                              hipStream_t stream){
  const float* x   = (const float*)d_in[0];
  const int*   msk = (const int*)d_in[1];
  const float* W1  = (const float*)d_in[2];
  const float* b1  = (const float*)d_in[3];
  const float* W2  = (const float*)d_in[4];
  const float* b2  = (const float*)d_in[5];
  const float* A1  = (const float*)d_in[6];
  const float* ab1 = (const float*)d_in[7];
  const float* A2  = (const float*)d_in[8];
  // d_in[9] = ab2: additive constant on logits, softmax-invariant -> unused
  const float* U1  = (const float*)d_in[10];
  const float* ub1 = (const float*)d_in[11];
  const float* U2  = (const float*)d_in[12];
  const float* ub2 = (const float*)d_in[13];
  float* out = (float*)d_out;

  char* w = (char*)d_ws;
  float*    Pm   = (float*)(w);                        // 2 MB (4096x128 f32)
  float*    Pa   = (float*)(w + (2u<<20));             // 2 MB
  uint32_t* Qmp  = (uint32_t*)(w + (4u<<20));          // 1 MB packed bf16 pairs
  uint32_t* QaTp = (uint32_t*)(w + (5u<<20));          // 1 MB
  float*    attn = (float*)(w + (6u<<20));             // 2 MB (32x128x128 f32)
  float*    hbar = (float*)(w + (8u<<20));             // 2 MB
  float*    M    = (float*)(w + (10u<<20));            // 64 KB
  float*    c0   = (float*)(w + (10u<<20) + (64u<<10));// 512 B

  hipLaunchKernelGGL(k0_precompose, dim3(129), dim3(128), 0, stream,
                     W2, b2, U1, ub1, M, c0);
  hipLaunchKernelGGL(k1_proj, dim3(16,32), dim3(128), 0, stream,
                     x, W1, b1, A1, ab1, Pm, Pa, Qmp, QaTp);
  hipLaunchKernelGGL(k2a_attn, dim3(16,32), dim3(256), 0, stream,
                     Pa, QaTp, A2, msk, attn);
  hipLaunchKernelGGL(k2b_hbar, dim3(16,32), dim3(256), 0, stream,
                     Pm, Qmp, attn, hbar);
  hipLaunchKernelGGL(k3_update, dim3(256), dim3(256), 0, stream,
                     x, hbar, M, c0, U1, U2, ub2, out);
}

// Round 3
// 124.977 us; speedup vs baseline: 1.1626x; 1.1626x over previous
//
#include <hip/hip_runtime.h>
#include <hip/hip_bf16.h>
#include <stdint.h>

#define NN 128
#define DD 64
#define HH 128

__device__ __forceinline__ float bflo(uint32_t u){ union{uint32_t u;float f;} c; c.u = u<<16; return c.f; }
__device__ __forceinline__ float bfhi(uint32_t u){ union{uint32_t u;float f;} c; c.u = u & 0xffff0000u; return c.f; }
__device__ __forceinline__ uint32_t packbf(float lo, float hi){
  __hip_bfloat16 a = __float2bfloat16(lo);
  __hip_bfloat16 b = __float2bfloat16(hi);
  uint16_t ua = *(uint16_t*)&a, ub = *(uint16_t*)&b;
  return (uint32_t)ua | ((uint32_t)ub<<16);
}

// K1 (fused with old K0):
//  blocks 0..511   : Pm = x@W1[:64]+b1, Qm = x@W1[64:], Pa = x@A1[:64]+ab1, Qa = x@A1[64:]
//                    Qm/Qa packed bf16 (h,h+64) per dword, layout [b][j][hp] -- coalesced stores
//  blocks 512..640 : M = W2@U1[64:], c0 = b2@U1[64:]+ub1  (update-net precomposition)
__global__ __launch_bounds__(128) void k1_proj(
    const float* __restrict__ x,
    const float* __restrict__ W1, const float* __restrict__ b1,
    const float* __restrict__ A1, const float* __restrict__ ab1,
    const float* __restrict__ W2, const float* __restrict__ b2,
    const float* __restrict__ U1, const float* __restrict__ ub1,
    float* __restrict__ Pm, float* __restrict__ Pa,
    uint32_t* __restrict__ Qmp, uint32_t* __restrict__ Qap,
    float* __restrict__ M, float* __restrict__ c0){
  const int bid = blockIdx.x;
  const int t = threadIdx.x;           // 0..127
  if(bid >= 512){                      // ---- old K0 ----
    int hb = bid - 512;                // 0..128
    if(hb < HH){
      float acc = 0.f;
      #pragma unroll 4
      for(int k=0;k<HH;k++) acc += W2[hb*HH+k] * U1[(DD+k)*HH+t];
      M[hb*HH+t] = acc;
    } else {
      float acc = ub1[t];
      #pragma unroll 4
      for(int k=0;k<HH;k++) acc += b2[k] * U1[(DD+k)*HH+t];
      c0[t] = acc;
    }
    return;
  }
  const int g = bid & 15, b = bid >> 4;
  const int jb = g*4;
  __shared__ float xs[8][64];     // rows: jb..jb+3, jb+64..jb+67
  __shared__ float qmS[8][128];
  __shared__ float qaS[8][128];
  {
    int r = t >> 4, d4 = (t & 15)*4;
    int gr = (r<4) ? (jb+r) : (jb + r - 4 + 64);
    *(float4*)&xs[r][d4] = *(const float4*)&x[(b*NN+gr)*DD + d4];
  }
  __syncthreads();
  float pm[8], qm[8], pa[8], qa[8];
  #pragma unroll
  for(int r=0;r<8;r++){ pm[r]=0.f;qm[r]=0.f;pa[r]=0.f;qa[r]=0.f; }
  for(int d0=0; d0<DD; d0+=4){
    float4 xr[8];
    #pragma unroll
    for(int r=0;r<8;r++) xr[r] = *(const float4*)&xs[r][d0];
    #pragma unroll
    for(int dd=0; dd<4; dd++){
      const int d = d0 + dd;
      float w1a = W1[d*HH + t];
      float w1b = W1[(DD+d)*HH + t];
      float a1a = A1[d*HH + t];
      float a1b = A1[(DD+d)*HH + t];
      #pragma unroll
      for(int r=0;r<8;r++){
        float xv = (&xr[r].x)[dd];
        pm[r] += xv*w1a; qm[r] += xv*w1b;
        pa[r] += xv*a1a; qa[r] += xv*a1b;
      }
    }
  }
  float b1v = b1[t], ab1v = ab1[t];
  #pragma unroll
  for(int r=0;r<8;r++){
    int gr = (r<4) ? (jb+r) : (jb + r - 4 + 64);
    Pm[(b*NN+gr)*HH + t] = pm[r] + b1v;
    Pa[(b*NN+gr)*HH + t] = pa[r] + ab1v;
    qmS[r][t] = qm[r];
    qaS[r][t] = qa[r];
  }
  __syncthreads();
  // pack (h, h+64) pairs; coalesced global stores
  #pragma unroll
  for(int k=0;k<4;k++){
    int idx = t + k*128;              // 0..511
    int r = idx >> 6, hp = idx & 63;
    int gr = (r<4) ? (jb+r) : (jb + r - 4 + 64);
    Qmp[(b*NN+gr)*64 + hp] = packbf(qmS[r][hp], qmS[r][hp+64]);
    Qap[(b*NN+gr)*64 + hp] = packbf(qaS[r][hp], qaS[r][hp+64]);
  }
}

// K2 (fused attn + hbar): per block = (batch b, 8 i-rows)
//  phase 1: logits_ij = sum_h relu(Pa_i[h]+Qa_j[h])*A2[h]; masked softmax -> atS (LDS)
//  phase 2: hbar_i[h] = sum_j attn_ij * relu(Pm_i[h]+Qm_j[h])
// qbuf rows padded to 65 dwords: bank = (row+col)%32 -> 2-way alias only (free).
__global__ __launch_bounds__(256) void k2_attn_hbar(
    const float* __restrict__ Pa, const float* __restrict__ Pm,
    const uint32_t* __restrict__ Qap, const uint32_t* __restrict__ Qmp,
    const float* __restrict__ A2, const int* __restrict__ masks,
    float* __restrict__ hbar){
  const int it = blockIdx.x;     // 0..15 (8 i each)
  const int b  = blockIdx.y;     // 0..31
  const int t = threadIdx.x;     // 0..255
  const int wave = t>>6, lane = t&63;
  __shared__ uint32_t qbuf[NN*65];   // 33.3 KB, padded rows
  __shared__ float pS[8*HH];         // Pa rows, then Pm rows
  __shared__ float a2S[HH];
  __shared__ float atS[8*NN];        // attention weights
  {
    const uint32_t* src = Qap + (size_t)b*NN*64;
    #pragma unroll
    for(int k=0;k<8;k++){
      int idx4 = t + k*256;                  // 0..2047 (uint4 index)
      int j = idx4 >> 4, hp4 = (idx4 & 15)*4;
      uint4 v = *(const uint4*)&src[j*64 + hp4];
      uint32_t* d = &qbuf[j*65 + hp4];
      d[0]=v.x; d[1]=v.y; d[2]=v.z; d[3]=v.w;
    }
    int r = t>>5, h4 = (t&31)*4;
    *(float4*)&pS[r*HH + h4] = *(const float4*)&Pa[(b*NN + it*8 + r)*HH + h4];
    if(t < HH) a2S[t] = A2[t];
  }
  __syncthreads();
  const int i0 = wave*2, i1 = i0+1;
  float a00=0.f,a01=0.f,a10=0.f,a11=0.f;   // (i0,jl),(i0,jh),(i1,jl),(i1,jh)
  for(int h0=0; h0<64; h0+=4){
    float4 p0a = *(const float4*)&pS[i0*HH + h0];
    float4 p0b = *(const float4*)&pS[i0*HH + 64 + h0];
    float4 p1a = *(const float4*)&pS[i1*HH + h0];
    float4 p1b = *(const float4*)&pS[i1*HH + 64 + h0];
    float4 a2a = *(const float4*)&a2S[h0];
    float4 a2b = *(const float4*)&a2S[64 + h0];
    #pragma unroll
    for(int dd=0; dd<4; dd++){
      uint32_t q0 = qbuf[lane*65 + h0 + dd];        // j = lane
      uint32_t q1 = qbuf[(lane+64)*65 + h0 + dd];   // j = lane+64
      float q0l=bflo(q0), q0h=bfhi(q0), q1l=bflo(q1), q1h=bfhi(q1);
      float pa0=(&p0a.x)[dd], pb0=(&p0b.x)[dd];
      float pa1=(&p1a.x)[dd], pb1=(&p1b.x)[dd];
      float aa=(&a2a.x)[dd],  ab=(&a2b.x)[dd];
      a00 += fmaxf(pa0+q0l,0.f)*aa; a00 += fmaxf(pb0+q0h,0.f)*ab;
      a01 += fmaxf(pa0+q1l,0.f)*aa; a01 += fmaxf(pb0+q1h,0.f)*ab;
      a10 += fmaxf(pa1+q0l,0.f)*aa; a10 += fmaxf(pb1+q0h,0.f)*ab;
      a11 += fmaxf(pa1+q1l,0.f)*aa; a11 += fmaxf(pb1+q1h,0.f)*ab;
    }
  }
  const int m0 = masks[b*NN + lane];
  const int m1 = masks[b*NN + 64 + lane];
  const float NEG = -3.0e38f;
  #pragma unroll
  for(int ii=0; ii<2; ii++){
    float x0 = ii ? a10 : a00, x1 = ii ? a11 : a01;
    int il = ii ? i1 : i0;
    float l0 = m0 ? x0 : NEG, l1 = m1 ? x1 : NEG;
    float v = fmaxf(l0, l1);
    for(int off=32; off>=1; off>>=1) v = fmaxf(v, __shfl_xor(v, off));
    float e0 = m0 ? __expf(x0 - v) : 0.f;
    float e1 = m1 ? __expf(x1 - v) : 0.f;
    float s = e0 + e1;
    for(int off=32; off>=1; off>>=1) s += __shfl_xor(s, off);
    float inv = (s > 0.f) ? (1.f/s) : 0.f;
    atS[il*NN + lane]      = e0*inv;
    atS[il*NN + 64 + lane] = e1*inv;
  }
  __syncthreads();   // phase-1 reads of qbuf/pS complete; atS visible
  {
    const uint32_t* src = Qmp + (size_t)b*NN*64;
    #pragma unroll
    for(int k=0;k<8;k++){
      int idx4 = t + k*256;
      int j = idx4 >> 4, hp4 = (idx4 & 15)*4;
      uint4 v = *(const uint4*)&src[j*64 + hp4];
      uint32_t* d = &qbuf[j*65 + hp4];
      d[0]=v.x; d[1]=v.y; d[2]=v.z; d[3]=v.w;
    }
    int r = t>>5, h4 = (t&31)*4;
    *(float4*)&pS[r*HH + h4] = *(const float4*)&Pm[(b*NN + it*8 + r)*HH + h4];
  }
  __syncthreads();
  float pm00 = pS[i0*HH + lane], pm01 = pS[i0*HH + 64 + lane];
  float pm10 = pS[i1*HH + lane], pm11 = pS[i1*HH + 64 + lane];
  float h00=0.f,h01=0.f,h10=0.f,h11=0.f;
  for(int j0=0; j0<NN; j0+=4){
    float4 at0 = *(const float4*)&atS[i0*NN + j0];
    float4 at1 = *(const float4*)&atS[i1*NN + j0];
    #pragma unroll
    for(int dd=0; dd<4; dd++){
      uint32_t qd = qbuf[(j0+dd)*65 + lane];   // h = lane / lane+64
      float ql = bflo(qd), qh = bfhi(qd);
      float w0 = (&at0.x)[dd], w1 = (&at1.x)[dd];
      h00 += w0*fmaxf(pm00+ql,0.f);
      h01 += w0*fmaxf(pm01+qh,0.f);
      h10 += w1*fmaxf(pm10+ql,0.f);
      h11 += w1*fmaxf(pm11+qh,0.f);
    }
  }
  const int gi0 = b*NN + it*8 + i0, gi1 = gi0 + 1;
  hbar[gi0*HH + lane]      = h00;
  hbar[gi0*HH + 64 + lane] = h01;
  hbar[gi1*HH + lane]      = h10;
  hbar[gi1*HH + 64 + lane] = h11;
}

// K3: hidden = relu(x@U1[:64] + hbar@M + c0); out = x + hidden@U2 + ub2
__global__ __launch_bounds__(256) void k3_update(
    const float* __restrict__ x, const float* __restrict__ hbar,
    const float* __restrict__ M, const float* __restrict__ c0,
    const float* __restrict__ U1, const float* __restrict__ U2,
    const float* __restrict__ ub2, float* __restrict__ out){
  const int bid = blockIdx.x;   // 0..255, 16 rows each
  const int t = threadIdx.x;    // 0..255
  const int r0 = bid*16;
  __shared__ float xs[16][64];
  __shared__ float hb[16][128];
  __shared__ float hidS[16][128];
  __shared__ float c0S[128];
  {
    int r = t>>4, d4 = (t&15)*4;
    *(float4*)&xs[r][d4] = *(const float4*)&x[(r0+r)*DD + d4];
    int r1 = t>>5, h4 = (t&31)*4;
    *(float4*)&hb[r1][h4]   = *(const float4*)&hbar[(r0+r1)*HH + h4];
    *(float4*)&hb[r1+8][h4] = *(const float4*)&hbar[(r0+r1+8)*HH + h4];
    if(t<128) c0S[t] = c0[t];
  }
  __syncthreads();
  {
    const int c = t & 127, g = t>>7;   // g: row-group of 8
    float acc[8];
    #pragma unroll
    for(int r=0;r<8;r++) acc[r]=0.f;
    for(int d0=0; d0<DD; d0+=4){
      float4 xr[8];
      #pragma unroll
      for(int r=0;r<8;r++) xr[r] = *(const float4*)&xs[g*8+r][d0];
      #pragma unroll
      for(int dd=0; dd<4; dd++){
        float u = U1[(d0+dd)*HH + c];
        #pragma unroll
        for(int r=0;r<8;r++) acc[r] += (&xr[r].x)[dd]*u;
      }
    }
    for(int h0=0; h0<HH; h0+=4){
      float4 hr[8];
      #pragma unroll
      for(int r=0;r<8;r++) hr[r] = *(const float4*)&hb[g*8+r][h0];
      #pragma unroll
      for(int dd=0; dd<4; dd++){
        float mv = M[(h0+dd)*HH + c];
        #pragma unroll
        for(int r=0;r<8;r++) acc[r] += (&hr[r].x)[dd]*mv;
      }
    }
    float cc = c0S[c];
    #pragma unroll
    for(int r=0;r<8;r++) hidS[g*8+r][c] = fmaxf(acc[r]+cc, 0.f);
  }
  __syncthreads();
  {
    const int dcol = t & 63, rg = t>>6;  // rg: row-group of 4
    float acc2[4];
    #pragma unroll
    for(int r=0;r<4;r++) acc2[r]=0.f;
    for(int ci=0; ci<HH; ci+=4){
      float4 hr[4];
      #pragma unroll
      for(int r=0;r<4;r++) hr[r] = *(const float4*)&hidS[rg*4+r][ci];
      #pragma unroll
      for(int dd=0; dd<4; dd++){
        float u2 = U2[(ci+dd)*DD + dcol];
        #pragma unroll
        for(int r=0;r<4;r++) acc2[r] += (&hr[r].x)[dd]*u2;
      }
    }
    float ub = ub2[dcol];
    #pragma unroll
    for(int r=0;r<4;r++){
      int row = r0 + rg*4 + r;
      out[row*DD + dcol] = xs[rg*4+r][dcol] + acc2[r] + ub;
    }
  }
}

extern "C" void kernel_launch(void* const* d_in, const int* in_sizes, int n_in,
                              void* d_out, int out_size, void* d_ws, size_t ws_size,
                              hipStream_t stream){
  const float* x   = (const float*)d_in[0];
  const int*   msk = (const int*)d_in[1];
  const float* W1  = (const float*)d_in[2];
  const float* b1  = (const float*)d_in[3];
  const float* W2  = (const float*)d_in[4];
  const float* b2  = (const float*)d_in[5];
  const float* A1  = (const float*)d_in[6];
  const float* ab1 = (const float*)d_in[7];
  const float* A2  = (const float*)d_in[8];
  // d_in[9] = ab2: additive constant on logits, softmax-invariant -> unused
  const float* U1  = (const float*)d_in[10];
  const float* ub1 = (const float*)d_in[11];
  const float* U2  = (const float*)d_in[12];
  const float* ub2 = (const float*)d_in[13];
  float* out = (float*)d_out;

  char* w = (char*)d_ws;
  float*    Pm   = (float*)(w);                        // 2 MB
  float*    Pa   = (float*)(w + (2u<<20));             // 2 MB
  uint32_t* Qmp  = (uint32_t*)(w + (4u<<20));          // 1 MB packed bf16 pairs
  uint32_t* Qap  = (uint32_t*)(w + (5u<<20));          // 1 MB
  float*    hbar = (float*)(w + (6u<<20));             // 2 MB
  float*    M    = (float*)(w + (8u<<20));             // 64 KB
  float*    c0   = (float*)(w + (8u<<20) + (64u<<10)); // 512 B

  hipLaunchKernelGGL(k1_proj, dim3(641), dim3(128), 0, stream,
                     x, W1, b1, A1, ab1, W2, b2, U1, ub1,
                     Pm, Pa, Qmp, Qap, M, c0);
  hipLaunchKernelGGL(k2_attn_hbar, dim3(16,32), dim3(256), 0, stream,
                     Pa, Pm, Qap, Qmp, A2, msk, hbar);
  hipLaunchKernelGGL(k3_update, dim3(256), dim3(256), 0, stream,
                     x, hbar, M, c0, U1, U2, ub2, out);
}